// Round 9
// baseline (529.892 us; speedup 1.0000x reference)
//
#include <hip/hip_runtime.h>
#include <hip/hip_bf16.h>
#include <math.h>

// HyenaFilter2D: out = u*D + 9-tap shifted conv (see derivation in earlier rounds).
// Gaussian modulation exp(-0.5*(r^2/delta)^2), delta in [0.1,0.3], kills all kernel
// taps except the 3x3 neighborhood of (256,256); double FFT normalization scales the
// conv by 1/2^20. Valid shifted reads require out row i>=255 AND col j>=255
// (bottom-right quadrant), reading u rows/cols [0,256].
//
// Round 9: SINGLE dispatch. Block 0 computes the 9x32 taps cooperatively and
// publishes them via an agent-scope release flag; blocks 1..2048 stream one
// 16-row chunk each (8 preloaded float4/thread). Conv blocks (sub>=15) preload
// first, then spin (lane 0, agent-acquire) until taps are published. Deadlock-
// free without co-residency assumptions: spinner blocks (<=1088) can never
// occupy all block slots; stream blocks retire unconditionally, so block 0 is
// always eventually scheduled. Flag sentinel != 0xAA poison; ws re-poisoned
// before every launch so the flag is reset each call.

#define HDIM 512
#define WDIM 512
#define CDIM 32
#define BDIM 2
#define HW   (HDIM*WDIM)
#define NBLOCK 2048               // 32 chunks per (b,c) image, 16 rows each
#define TAPS_MAGIC 0x5F3759DFu

__global__ __launch_bounds__(256) void hyena_fused_kernel(
    const float* __restrict__ u,      // [B, C, 512, 512]
    const float* __restrict__ zh,     // [512, 5]
    const float* __restrict__ zw,     // [512, 5]
    const float* __restrict__ W0,     // [10, 64]
    const float* __restrict__ b0,     // [64]
    const float* __restrict__ W1,     // [64, 64]
    const float* __restrict__ b1,     // [64]
    const float* __restrict__ W2,     // [64, 64]
    const float* __restrict__ b2,     // [64]
    const float* __restrict__ Wout,   // [64, 32]
    const float* __restrict__ freq,   // [64]
    const float* __restrict__ deltas, // [32]
    const float* __restrict__ D,      // [32]
    float* __restrict__ out,          // [B, C, 512, 512]
    float* __restrict__ taps,         // ws: [9][32] floats
    unsigned int* __restrict__ flag)  // ws: 1 uint after taps
{
    const int block = blockIdx.x;
    const int t = threadIdx.x;

    if (block == 0) {
        // ---- cooperative taps: 9 positions x 64 hidden over 256 threads ----
        __shared__ float HA[576];
        __shared__ float HB[576];
        for (int n = t; n < 576; n += 256) {
            int p = n >> 6, o = n & 63;
            int di = p / 3 - 1, dj = p % 3 - 1;
            float acc = b0[o];
            #pragma unroll
            for (int e = 0; e < 5; e++) acc += zh[(256 + di) * 5 + e] * W0[e * 64 + o];
            #pragma unroll
            for (int e = 0; e < 5; e++) acc += zw[(256 + dj) * 5 + e] * W0[(5 + e) * 64 + o];
            HA[n] = sinf(freq[o] * acc);
        }
        __syncthreads();
        for (int n = t; n < 576; n += 256) {
            int p = n >> 6, o = n & 63;
            float acc = b1[o];
            #pragma unroll 8
            for (int e = 0; e < 64; e++) acc += HA[(p << 6) + e] * W1[e * 64 + o];
            HB[n] = sinf(freq[o] * acc);
        }
        __syncthreads();
        for (int n = t; n < 576; n += 256) {
            int p = n >> 6, o = n & 63;
            float acc = b2[o];
            #pragma unroll 8
            for (int e = 0; e < 64; e++) acc += HB[(p << 6) + e] * W2[e * 64 + o];
            HA[n] = sinf(freq[o] * acc);
        }
        __syncthreads();
        if (t < 288) {
            int p = t >> 5, c = t & 31;
            int di = p / 3 - 1, dj = p % 3 - 1;
            float acc = 0.0f;
            #pragma unroll 8
            for (int e = 0; e < 64; e++) acc += HA[(p << 6) + e] * Wout[e * 32 + c];
            float delta = deltas[c];
            float r2 = (float)(di * di + dj * dj);
            float q = r2 / delta;
            float scaler = expf(-0.5f * q * q) / (delta * 2.5066282746310002f);
            // agent-scope store so consumers' relaxed-agent loads see it
            __hip_atomic_store(&taps[p * 32 + c], acc * scaler * (1.0f / (1024.0f * 1024.0f)),
                               __ATOMIC_RELAXED, __HIP_MEMORY_SCOPE_AGENT);
        }
        __syncthreads();
        if (t == 0) {
            __threadfence();  // device-scope release of the taps stores
            __hip_atomic_store(flag, TAPS_MAGIC, __ATOMIC_RELEASE, __HIP_MEMORY_SCOPE_AGENT);
        }
        return;
    }

    const int chunk = block - 1;             // 0..2047
    const int bc  = chunk >> 5;              // b*32 + c
    const int c   = bc & 31;
    const int sub = chunk & 31;              // rows [sub*16, sub*16+16)

    const int g0  = (chunk << 11) + t;       // first float4 group of this thread
    const float* __restrict__ up = u + (g0 << 2);

    // ---- branch-free preload: 8 independent float4 loads in flight ----
    float4 v[8];
    #pragma unroll
    for (int k = 0; k < 8; ++k)
        v[k] = *reinterpret_cast<const float4*>(up + (k << 10));  // +1024 floats = 2 rows

    const float d = D[c];
    #pragma unroll
    for (int k = 0; k < 8; ++k) {
        v[k].x *= d; v[k].y *= d; v[k].z *= d; v[k].w *= d;
    }

    // ---- conv fixup: quadrant (row>=255, out col>=255) ----
    const int j0     = (t & 127) << 2;       // col of this thread's groups
    const int i_base = (sub << 4) + (t >> 7);
    if (sub >= 15) {
        // wait for taps (block-uniform branch; lane 0 spins, then barrier)
        if (t == 0) {
            while (__hip_atomic_load(flag, __ATOMIC_ACQUIRE, __HIP_MEMORY_SCOPE_AGENT)
                   != TAPS_MAGIC) {
                __builtin_amdgcn_s_sleep(4);
            }
        }
        __syncthreads();

        const float* __restrict__ ubase = u + bc * HW;
        if (j0 >= 256) {
            // wave-uniform full conv body (lanes 64..127 of each 128-half)
            float tp[9];
            #pragma unroll
            for (int p = 0; p < 9; ++p)
                tp[p] = __hip_atomic_load(&taps[p * 32 + c],
                                          __ATOMIC_RELAXED, __HIP_MEMORY_SCOPE_AGENT);

            #pragma unroll
            for (int k = 0; k < 8; ++k) {
                int i = i_base + (k << 1);
                if (i < 255) continue;
                #pragma unroll
                for (int a = 0; a < 3; ++a) {
                    int si = i - 255 - a;            // source row, 0..256
                    if (si < 0) continue;
                    const float* row = ubase + si * WDIM;
                    float w[6];                      // w[m] = row[j0-257+m]
                    w[0] = (j0 >= 260) ? row[j0 - 257] : 0.0f;
                    const float4 Bv = *reinterpret_cast<const float4*>(row + j0 - 256);
                    w[1] = Bv.x; w[2] = Bv.y; w[3] = Bv.z; w[4] = Bv.w;
                    w[5] = row[j0 - 252];
                    #pragma unroll
                    for (int bb = 0; bb < 3; ++bb) {
                        float tv = tp[a * 3 + bb];
                        v[k].x += tv * w[2 - bb + 0];
                        v[k].y += tv * w[2 - bb + 1];
                        v[k].z += tv * w[2 - bb + 2];
                        v[k].w += tv * w[2 - bb + 3];
                    }
                }
            }
        } else if (j0 == 252) {
            // straggler lane: output col 255 only; only dj=-1 taps (p=3a), u[si][0]
            float tp3[3];
            #pragma unroll
            for (int a = 0; a < 3; ++a)
                tp3[a] = __hip_atomic_load(&taps[(a * 3) * 32 + c],
                                           __ATOMIC_RELAXED, __HIP_MEMORY_SCOPE_AGENT);
            #pragma unroll
            for (int k = 0; k < 8; ++k) {
                int i = i_base + (k << 1);
                if (i < 255) continue;
                #pragma unroll
                for (int a = 0; a < 3; ++a) {
                    int si = i - 255 - a;
                    if (si < 0) continue;
                    v[k].w += tp3[a] * ubase[si * WDIM];
                }
            }
        }
    }

    // ---- stores ----
    float* __restrict__ op = out + (g0 << 2);
    #pragma unroll
    for (int k = 0; k < 8; ++k)
        *reinterpret_cast<float4*>(op + (k << 10)) = v[k];
}

extern "C" void kernel_launch(void* const* d_in, const int* in_sizes, int n_in,
                              void* d_out, int out_size, void* d_ws, size_t ws_size,
                              hipStream_t stream) {
    const float* u      = (const float*)d_in[0];
    const float* zh     = (const float*)d_in[1];
    const float* zw     = (const float*)d_in[2];
    const float* W0     = (const float*)d_in[3];
    const float* b0     = (const float*)d_in[4];
    const float* W1     = (const float*)d_in[5];
    const float* b1     = (const float*)d_in[6];
    const float* W2     = (const float*)d_in[7];
    const float* b2     = (const float*)d_in[8];
    const float* Wout   = (const float*)d_in[9];
    const float* freq   = (const float*)d_in[10];
    const float* deltas = (const float*)d_in[11];
    const float* D      = (const float*)d_in[12];
    float* out  = (float*)d_out;
    float* taps = (float*)d_ws;                       // 288 floats
    unsigned int* flag = (unsigned int*)(taps + 288); // 1 uint

    hyena_fused_kernel<<<NBLOCK + 1, 256, 0, stream>>>(u, zh, zw, W0, b0, W1, b1,
                                                       W2, b2, Wout, freq, deltas,
                                                       D, out, taps, flag);
}